// Round 9
// baseline (193.282 us; speedup 1.0000x reference)
//
#include <hip/hip_runtime.h>

#define B_ 2
#define C_ 256
#define HW_ 64
#define N_ 4096
#define K_SEL 1228   // int(4096*0.3)
#define MIP_ 16
#define MAGICU 0x5ca1f1a6u

__device__ __forceinline__ float sigm(float z) { return 1.0f / (1.0f + expf(-z)); }

// Single kernel: 512 blocks x 256 threads, guaranteed co-resident (2 blocks/CU).
// Pools -> flags; one designated block per batch does conv+sigmoids -> done;
// everyone proceeds to selection + moments + output.
__global__ __launch_bounds__(256, 2) void k_one(
    const float* __restrict__ x,
    const float* __restrict__ w1, const float* __restrict__ b1,
    const float* __restrict__ gam, const float* __restrict__ bet,
    const float* __restrict__ mea, const float* __restrict__ var,
    const float* __restrict__ wh, const float* __restrict__ bh,
    const float* __restrict__ ww, const float* __restrict__ bw,
    const float* __restrict__ wd1, const float* __restrict__ bd1,
    const float* __restrict__ wd2, const float* __restrict__ bd2,
    const float* __restrict__ msk,
    float* __restrict__ xhT, float* __restrict__ flags,
    float* __restrict__ ahsp, float* __restrict__ done,
    float* __restrict__ out) {
  __shared__ float cwp[4][HW_];
  __shared__ float dpart[2][128][4];
  __shared__ float ahs[HW_], sds[HW_], sws[HW_], sps[HW_];
  __shared__ int icomb[4];
  __shared__ float fmn[4], fmx[4];
  __shared__ float red[15][4];
  __shared__ float ps[15];

  int bc = blockIdx.x, t = threadIdx.x;
  int b = bc >> 8, c = bc & 255;
  int wv = t >> 6, l = t & 63;

  // ========== Stage A: image -> registers, row/col means -> xhT (atomics)
  const float* xr = x + (size_t)bc * N_;
  float4 xv[4];
  #pragma unroll
  for (int it = 0; it < 4; ++it)
    xv[it] = *(const float4*)&xr[it * 1024 + t * 4];

  float cse[4] = {0, 0, 0, 0};
  #pragma unroll
  for (int it = 0; it < 4; ++it) {
    float s = xv[it].x + xv[it].y + xv[it].z + xv[it].w;
    s += __shfl_xor(s, 1, 64);
    s += __shfl_xor(s, 2, 64);
    s += __shfl_xor(s, 4, 64);
    s += __shfl_xor(s, 8, 64);
    if ((t & 15) == 0) {
      int h = it * 16 + (t >> 4);
      atomicExch(&xhT[(((b * 2 + 0) * 64 + h) << 8) + c], s * (1.0f / 64.0f));
    }
    cse[0] += xv[it].x; cse[1] += xv[it].y;
    cse[2] += xv[it].z; cse[3] += xv[it].w;
  }
  #pragma unroll
  for (int e = 0; e < 4; ++e) {
    cse[e] += __shfl_xor(cse[e], 16, 64);
    cse[e] += __shfl_xor(cse[e], 32, 64);
  }
  if (l < 16) {
    #pragma unroll
    for (int e = 0; e < 4; ++e) cwp[wv][4 * l + e] = cse[e];
  }
  __syncthreads();
  if (t < 64) {
    float cw = cwp[0][t] + cwp[1][t] + cwp[2][t] + cwp[3][t];
    atomicExch(&xhT[(((b * 2 + 1) * 64 + t) << 8) + c], cw * (1.0f / 64.0f));
  }
  __syncthreads();   // all pool atomics issued before flag
  if (t == 0) atomicExch(&flags[bc], __uint_as_float(MAGICU));

  // ========== Stage B: designated block per batch does conv+dots+sigmoids
  if ((bc & 255) == 0) {
    // wait for this batch's 256 producers (lane-per-flag)
    {
      float* fl = &flags[(b << 8) + t];
      while (__float_as_uint(atomicAdd(fl, 0.0f)) != MAGICU)
        __builtin_amdgcn_s_sleep(4);
    }
    __syncthreads();
    {
      int p = t & 127;
      int oh = __builtin_amdgcn_readfirstlane(t >> 7);   // wave-uniform
      int seg = p >> 6, pos = p & 63;
      const float* yrow = xhT + (((b * 2 + seg) * 64 + pos) << 8);
      const float* wb = w1 + oh * 8 * C_;                // uniform -> s_loads
      float r8[8] = {0, 0, 0, 0, 0, 0, 0, 0};
      #pragma unroll 4
      for (int c4 = 0; c4 < 64; ++c4) {
        float4 y4 = *(const float4*)&yrow[c4 * 4];
        const float ye[4] = {y4.x, y4.y, y4.z, y4.w};
        #pragma unroll
        for (int e = 0; e < 4; ++e) {
          int cc = c4 * 4 + e;
          #pragma unroll
          for (int oo = 0; oo < 8; ++oo)
            r8[oo] = fmaf(wb[oo * C_ + cc], ye[e], r8[oo]);
        }
      }
      float dH = 0, dW = 0, dD1 = 0, dD2 = 0;
      #pragma unroll
      for (int oo = 0; oo < 8; ++oo) {
        int o = oh * 8 + oo;
        float sc = gam[o] * rsqrtf(var[o] + 1e-5f);
        float y = r8[oo] + b1[o] - mea[o];
        float rr = fmaxf(fmaf(y, sc, bet[o]), 0.0f);
        dH = fmaf(wh[o], rr, dH);
        dW = fmaf(ww[o], rr, dW);
        dD1 = fmaf(wd1[o], rr, dD1);
        dD2 = fmaf(wd2[o], rr, dD2);
      }
      dpart[oh][p][0] = dH; dpart[oh][p][1] = dW;
      dpart[oh][p][2] = dD1; dpart[oh][p][3] = dD2;
    }
    __syncthreads();
    if (t < 128) {
      int seg = t >> 6, pos = t & 63;
      float aH = bh[0] + dpart[0][t][0] + dpart[1][t][0];
      float aW = bw[0] + dpart[0][t][1] + dpart[1][t][1];
      float aD1 = bd1[0] + dpart[0][t][2] + dpart[1][t][2];
      float aD2 = bd2[0] + dpart[0][t][3] + dpart[1][t][3];
      if (seg == 0) {
        ahs[pos] = sigm(aH);
        sds[pos] = sigm(aD1) * sigm(aD2);
      } else {
        sws[pos] = sigm(aW);
      }
    }
    __syncthreads();
    if (t < 64) {
      atomicExch(&ahsp[b * 128 + t], ahs[t]);
      atomicExch(&ahsp[b * 128 + 64 + t], sws[t] * sds[t]);
    }
    __syncthreads();   // publish before done
    if (t == 0) atomicExch(&done[b], __uint_as_float(MAGICU));
  }

  // ========== all blocks: wait for conv result (single word, single lane)
  if (t == 0) {
    while (__float_as_uint(atomicAdd(&done[b], 0.0f)) != MAGICU)
      __builtin_amdgcn_s_sleep(16);
  }
  __syncthreads();
  if (t < 64) {
    ahs[t] = ahsp[b * 128 + t];
    sps[t] = ahsp[b * 128 + 64 + t];
  }
  __syncthreads();

  // ========== Stage C: selection + moments + output
  float4 sp4 = *(const float4*)&sps[(t * 4) & 63];
  const float spe[4] = {sp4.x, sp4.y, sp4.z, sp4.w};
  float ahv[4];
  #pragma unroll
  for (int it = 0; it < 4; ++it) ahv[it] = ahs[it * 16 + (t >> 4)];

  float v[16];
  #pragma unroll
  for (int it = 0; it < 4; ++it)
    #pragma unroll
    for (int e = 0; e < 4; ++e) v[it * 4 + e] = ahv[it] * spe[e];

  float mn = v[0], mx = v[0];
  #pragma unroll
  for (int k = 1; k < 16; ++k) { mn = fminf(mn, v[k]); mx = fmaxf(mx, v[k]); }
  #pragma unroll
  for (int o = 32; o; o >>= 1) {
    mn = fminf(mn, __shfl_xor(mn, o, 64));
    mx = fmaxf(mx, __shfl_xor(mx, o, 64));
  }
  if ((t & 63) == 0) { fmn[t >> 6] = mn; fmx[t >> 6] = mx; }
  __syncthreads();
  mn = fminf(fminf(fmn[0], fmn[1]), fminf(fmn[2], fmn[3]));
  mx = fmaxf(fmaxf(fmx[0], fmx[1]), fmaxf(fmx[2], fmx[3]));

  unsigned lo = __float_as_uint(mn);        // cnt_ge(lo) = 4096 >= K
  unsigned hi = __float_as_uint(mx) + 1u;   // cnt_ge(hi) = 0 < K
  while (hi - lo > 8192u) {
    unsigned mid = lo + ((hi - lo) >> 1);
    float midf = __uint_as_float(mid);
    int cnt = 0;
    #pragma unroll
    for (int k = 0; k < 16; ++k) cnt += (v[k] >= midf) ? 1 : 0;
    #pragma unroll
    for (int o = 32; o; o >>= 1) cnt += __shfl_xor(cnt, o, 64);
    if ((t & 63) == 0) icomb[t >> 6] = cnt;
    __syncthreads();
    int total = icomb[0] + icomb[1] + icomb[2] + icomb[3];
    __syncthreads();
    if (total >= K_SEL) lo = mid; else hi = mid;
  }
  float thr = __uint_as_float(lo);
  float gm = sigm(msk[0]);

  // acc[0..6] = q1..q7, acc[7] = T, acc[8..14] = P1..P7
  float acc[15];
  #pragma unroll
  for (int m = 0; m < 15; ++m) acc[m] = 0.0f;
  #pragma unroll
  for (int it = 0; it < 4; ++it) {
    const float xe[4] = {xv[it].x, xv[it].y, xv[it].z, xv[it].w};
    #pragma unroll
    for (int e = 0; e < 4; ++e) {
      float vv = v[it * 4 + e];
      float xx = xe[e];
      acc[7] += xx;
      if (vv >= thr) {
        float p = vv;
        acc[0] += p;
        acc[8] = fmaf(p, xx, acc[8]); p *= vv;
        acc[1] += p;
        acc[9] = fmaf(p, xx, acc[9]); p *= vv;
        acc[2] += p;
        acc[10] = fmaf(p, xx, acc[10]); p *= vv;
        acc[3] += p;
        acc[11] = fmaf(p, xx, acc[11]); p *= vv;
        acc[4] += p;
        acc[12] = fmaf(p, xx, acc[12]); p *= vv;
        acc[5] += p;
        acc[13] = fmaf(p, xx, acc[13]); p *= vv;
        acc[6] += p;
        acc[14] = fmaf(p, xx, acc[14]);
      }
    }
  }
  #pragma unroll
  for (int m = 0; m < 15; ++m) {
    float s = acc[m];
    #pragma unroll
    for (int o = 32; o; o >>= 1) s += __shfl_xor(s, o, 64);
    if ((t & 63) == 0) red[m][t >> 6] = s;
  }
  __syncthreads();
  if (t < 15) {
    const float invf[15] = {1.0f, 0.5f, 1.0f / 6.0f, 1.0f / 24.0f,
                            1.0f / 120.0f, 1.0f / 720.0f, 1.0f / 5040.0f,
                            1.0f,
                            1.0f, 0.5f, 1.0f / 6.0f, 1.0f / 24.0f,
                            1.0f / 120.0f, 1.0f / 720.0f, 1.0f / 5040.0f};
    ps[t] = (red[t][0] + red[t][1] + red[t][2] + red[t][3]) * invf[t];
  }
  __syncthreads();
  float q1 = ps[0], q2 = ps[1], q3 = ps[2], q4 = ps[3];
  float q5 = ps[4], q6 = ps[5], q7 = ps[6];
  float T = ps[7];
  float p1 = ps[8], p2 = ps[9], p3 = ps[10], p4 = ps[11];
  float p5 = ps[12], p6 = ps[13], p7 = ps[14];

  float* ob = out + (size_t)bc * N_;
  #pragma unroll
  for (int it = 0; it < 4; ++it) {
    float o4[4];
    #pragma unroll
    for (int e = 0; e < 4; ++e) {
      float alpha = gm * v[it * 4 + e];
      float hn = p7;
      hn = fmaf(alpha, hn, p6);
      hn = fmaf(alpha, hn, p5);
      hn = fmaf(alpha, hn, p4);
      hn = fmaf(alpha, hn, p3);
      hn = fmaf(alpha, hn, p2);
      hn = fmaf(alpha, hn, p1);
      float numer = fmaf(alpha, hn, T);
      float hd = q7;
      hd = fmaf(alpha, hd, q6);
      hd = fmaf(alpha, hd, q5);
      hd = fmaf(alpha, hd, q4);
      hd = fmaf(alpha, hd, q3);
      hd = fmaf(alpha, hd, q2);
      hd = fmaf(alpha, hd, q1);
      float denom = fmaf(alpha, hd, (float)N_);
      o4[e] = numer / denom;
    }
    *(float4*)&ob[it * 1024 + t * 4] = make_float4(o4[0], o4[1], o4[2], o4[3]);
  }
}

extern "C" void kernel_launch(void* const* d_in, const int* in_sizes, int n_in,
                              void* d_out, int out_size, void* d_ws, size_t ws_size,
                              hipStream_t stream) {
  (void)in_sizes; (void)n_in; (void)out_size; (void)ws_size;
  const float* x   = (const float*)d_in[0];
  const float* w1  = (const float*)d_in[1];
  const float* b1  = (const float*)d_in[2];
  const float* gam = (const float*)d_in[3];
  const float* bet = (const float*)d_in[4];
  const float* mea = (const float*)d_in[5];
  const float* var = (const float*)d_in[6];
  const float* wh  = (const float*)d_in[7];
  const float* bh  = (const float*)d_in[8];
  const float* ww  = (const float*)d_in[9];
  const float* bw  = (const float*)d_in[10];
  const float* wd1 = (const float*)d_in[11];
  const float* bd1 = (const float*)d_in[12];
  const float* wd2 = (const float*)d_in[13];
  const float* bd2 = (const float*)d_in[14];
  const float* msk = (const float*)d_in[15];
  float* out = (float*)d_out;

  float* ws    = (float*)d_ws;
  float* xhT   = ws;                 // 65536 floats
  float* flags = ws + 65536;         // 512
  float* ahsp  = ws + 66048;         // 256
  float* done  = ws + 66304;         // 2

  hipLaunchKernelGGL(k_one, dim3(B_ * C_), dim3(256), 0, stream,
                     x, w1, b1, gam, bet, mea, var,
                     wh, bh, ww, bw, wd1, bd1, wd2, bd2, msk,
                     xhT, flags, ahsp, done, out);
}

// Round 10
// 51.942 us; speedup vs baseline: 3.7211x; 3.7211x over previous
//
#include <hip/hip_runtime.h>

#define B_ 2
#define C_ 256
#define HW_ 64
#define N_ 4096
#define K_SEL 1228   // int(4096*0.3)
#define MIP_ 16
#define MAGICU 0x5ca1f1a6u

__device__ __forceinline__ float sigm(float z) { return 1.0f / (1.0f + expf(-z)); }

__device__ __forceinline__ unsigned acqload(const unsigned* p) {
  return __hip_atomic_load(p, __ATOMIC_ACQUIRE, __HIP_MEMORY_SCOPE_AGENT);
}
__device__ __forceinline__ void relstore(unsigned* p, unsigned v) {
  __hip_atomic_store(p, v, __ATOMIC_RELEASE, __HIP_MEMORY_SCOPE_AGENT);
}
__device__ __forceinline__ float ldagent(const float* p) {
  return __hip_atomic_load(p, __ATOMIC_RELAXED, __HIP_MEMORY_SCOPE_AGENT);
}
__device__ __forceinline__ void stagent(float* p, float v) {
  __hip_atomic_store(p, v, __ATOMIC_RELAXED, __HIP_MEMORY_SCOPE_AGENT);
}

// Single kernel: 512 blocks x 256 threads, all co-resident (2 blocks/CU).
// Producers publish pooled means; 128 row-workers/batch do the conv; all
// blocks then run selection + moments + output. Sync = release-store flags
// + acquire-load polling (no RMWs).
__global__ __launch_bounds__(256, 2) void k_one(
    const float* __restrict__ x,
    const float* __restrict__ w1, const float* __restrict__ b1,
    const float* __restrict__ gam, const float* __restrict__ bet,
    const float* __restrict__ mea, const float* __restrict__ var,
    const float* __restrict__ wh, const float* __restrict__ bh,
    const float* __restrict__ ww, const float* __restrict__ bw,
    const float* __restrict__ wd1, const float* __restrict__ bd1,
    const float* __restrict__ wd2, const float* __restrict__ bd2,
    const float* __restrict__ msk,
    float* __restrict__ xhT, unsigned* __restrict__ flags,
    unsigned* __restrict__ rowflags,
    float* __restrict__ ahb, float* __restrict__ swb, float* __restrict__ sdb,
    float* __restrict__ out) {
  __shared__ float cwp[4][HW_];
  __shared__ float ahs[HW_], sps[HW_];
  __shared__ int icomb[4];
  __shared__ float fmn[4], fmx[4];
  __shared__ float red[15][4];
  __shared__ float ps[15];

  int bc = blockIdx.x, t = threadIdx.x;
  int b = bc >> 8, cc = bc & 255;
  int wv = t >> 6, l = t & 63;

  // ========== Stage A: image -> registers, row/col means -> xhT
  const float* xr = x + (size_t)bc * N_;
  float4 xv[4];
  #pragma unroll
  for (int it = 0; it < 4; ++it)
    xv[it] = *(const float4*)&xr[it * 1024 + t * 4];

  float cse[4] = {0, 0, 0, 0};
  #pragma unroll
  for (int it = 0; it < 4; ++it) {
    float s = xv[it].x + xv[it].y + xv[it].z + xv[it].w;
    s += __shfl_xor(s, 1, 64);
    s += __shfl_xor(s, 2, 64);
    s += __shfl_xor(s, 4, 64);
    s += __shfl_xor(s, 8, 64);
    if ((t & 15) == 0) {
      int h = it * 16 + (t >> 4);
      stagent(&xhT[((b * 128 + h) << 8) + cc], s * (1.0f / 64.0f));
    }
    cse[0] += xv[it].x; cse[1] += xv[it].y;
    cse[2] += xv[it].z; cse[3] += xv[it].w;
  }
  #pragma unroll
  for (int e = 0; e < 4; ++e) {
    cse[e] += __shfl_xor(cse[e], 16, 64);
    cse[e] += __shfl_xor(cse[e], 32, 64);
  }
  if (l < 16) {
    #pragma unroll
    for (int e = 0; e < 4; ++e) cwp[wv][4 * l + e] = cse[e];
  }
  __syncthreads();
  if (t < 64) {
    float cw = cwp[0][t] + cwp[1][t] + cwp[2][t] + cwp[3][t];
    stagent(&xhT[((b * 128 + 64 + t) << 8) + cc], cw * (1.0f / 64.0f));
  }
  __syncthreads();   // all agent stores issued (vmcnt drained per wave)
  if (t == 0) relstore(&flags[bc], MAGICU);

  // ========== Stage B: row-workers (cc < 128): one conv row each
  if (cc < 128) {
    // wait for this batch's 256 producers (lane-per-flag acquire loads)
    {
      const unsigned* fl = &flags[(b << 8) + t];
      while (!__all(acqload(fl) == MAGICU)) __builtin_amdgcn_s_sleep(1);
    }
    __syncthreads();
    if (t < 64) {
      int p = cc;                      // seg = p>>6, pos = p&63
      const float* yrow = xhT + ((b * 128 + p) << 8);
      float4 y4 = *(const float4*)&yrow[t * 4];
      float r[MIP_];
      #pragma unroll
      for (int o = 0; o < MIP_; ++o) {
        float4 w4 = *(const float4*)&w1[o * C_ + t * 4];
        float s = fmaf(y4.x, w4.x, fmaf(y4.y, w4.y, fmaf(y4.z, w4.z, y4.w * w4.w)));
        #pragma unroll
        for (int off = 32; off; off >>= 1) s += __shfl_xor(s, off, 64);
        r[o] = s;
      }
      if (t == 0) {
        float aH = bh[0], aW = bw[0], aD1 = bd1[0], aD2 = bd2[0];
        #pragma unroll
        for (int o = 0; o < MIP_; ++o) {
          float sc = gam[o] * rsqrtf(var[o] + 1e-5f);
          float y = r[o] + b1[o] - mea[o];
          float rr = fmaxf(fmaf(y, sc, bet[o]), 0.0f);
          aH = fmaf(wh[o], rr, aH);
          aW = fmaf(ww[o], rr, aW);
          aD1 = fmaf(wd1[o], rr, aD1);
          aD2 = fmaf(wd2[o], rr, aD2);
        }
        int seg = p >> 6, pos = p & 63;
        if (seg == 0) {
          stagent(&ahb[b * HW_ + pos], sigm(aH));
          stagent(&sdb[b * HW_ + pos], sigm(aD1) * sigm(aD2));
        } else {
          stagent(&swb[b * HW_ + pos], sigm(aW));
        }
        relstore(&rowflags[(b << 7) + p], MAGICU);   // same thread: ordered
      }
    }
  }

  // ========== all blocks: wait for the 128 row results of this batch
  {
    const unsigned* rp = &rowflags[(b << 7) + (t & 127)];
    while (!__all(acqload(rp) == MAGICU)) __builtin_amdgcn_s_sleep(2);
  }
  __syncthreads();
  if (t < 64) {
    ahs[t] = ldagent(&ahb[b * HW_ + t]);
    sps[t] = ldagent(&swb[b * HW_ + t]) * ldagent(&sdb[b * HW_ + t]);
  }
  __syncthreads();

  // ========== Stage C: selection + moments + output
  float4 sp4 = *(const float4*)&sps[(t * 4) & 63];
  const float spe[4] = {sp4.x, sp4.y, sp4.z, sp4.w};
  float ahv[4];
  #pragma unroll
  for (int it = 0; it < 4; ++it) ahv[it] = ahs[it * 16 + (t >> 4)];

  float v[16];
  #pragma unroll
  for (int it = 0; it < 4; ++it)
    #pragma unroll
    for (int e = 0; e < 4; ++e) v[it * 4 + e] = ahv[it] * spe[e];

  float mn = v[0], mx = v[0];
  #pragma unroll
  for (int k = 1; k < 16; ++k) { mn = fminf(mn, v[k]); mx = fmaxf(mx, v[k]); }
  #pragma unroll
  for (int o = 32; o; o >>= 1) {
    mn = fminf(mn, __shfl_xor(mn, o, 64));
    mx = fmaxf(mx, __shfl_xor(mx, o, 64));
  }
  if ((t & 63) == 0) { fmn[t >> 6] = mn; fmx[t >> 6] = mx; }
  __syncthreads();
  mn = fminf(fminf(fmn[0], fmn[1]), fminf(fmn[2], fmn[3]));
  mx = fmaxf(fmaxf(fmx[0], fmx[1]), fmaxf(fmx[2], fmx[3]));

  unsigned lo = __float_as_uint(mn);        // cnt_ge(lo) = 4096 >= K
  unsigned hi = __float_as_uint(mx) + 1u;   // cnt_ge(hi) = 0 < K
  while (hi - lo > 8192u) {
    unsigned mid = lo + ((hi - lo) >> 1);
    float midf = __uint_as_float(mid);
    int cnt = 0;
    #pragma unroll
    for (int k = 0; k < 16; ++k) cnt += (v[k] >= midf) ? 1 : 0;
    #pragma unroll
    for (int o = 32; o; o >>= 1) cnt += __shfl_xor(cnt, o, 64);
    if ((t & 63) == 0) icomb[t >> 6] = cnt;
    __syncthreads();
    int total = icomb[0] + icomb[1] + icomb[2] + icomb[3];
    __syncthreads();
    if (total >= K_SEL) lo = mid; else hi = mid;
  }
  float thr = __uint_as_float(lo);
  float gm = sigm(msk[0]);

  // acc[0..6] = q1..q7, acc[7] = T, acc[8..14] = P1..P7
  float acc[15];
  #pragma unroll
  for (int m = 0; m < 15; ++m) acc[m] = 0.0f;
  #pragma unroll
  for (int it = 0; it < 4; ++it) {
    const float xe[4] = {xv[it].x, xv[it].y, xv[it].z, xv[it].w};
    #pragma unroll
    for (int e = 0; e < 4; ++e) {
      float vv = v[it * 4 + e];
      float xx = xe[e];
      acc[7] += xx;
      if (vv >= thr) {
        float p = vv;
        acc[0] += p;
        acc[8] = fmaf(p, xx, acc[8]); p *= vv;
        acc[1] += p;
        acc[9] = fmaf(p, xx, acc[9]); p *= vv;
        acc[2] += p;
        acc[10] = fmaf(p, xx, acc[10]); p *= vv;
        acc[3] += p;
        acc[11] = fmaf(p, xx, acc[11]); p *= vv;
        acc[4] += p;
        acc[12] = fmaf(p, xx, acc[12]); p *= vv;
        acc[5] += p;
        acc[13] = fmaf(p, xx, acc[13]); p *= vv;
        acc[6] += p;
        acc[14] = fmaf(p, xx, acc[14]);
      }
    }
  }
  #pragma unroll
  for (int m = 0; m < 15; ++m) {
    float s = acc[m];
    #pragma unroll
    for (int o = 32; o; o >>= 1) s += __shfl_xor(s, o, 64);
    if ((t & 63) == 0) red[m][t >> 6] = s;
  }
  __syncthreads();
  if (t < 15) {
    const float invf[15] = {1.0f, 0.5f, 1.0f / 6.0f, 1.0f / 24.0f,
                            1.0f / 120.0f, 1.0f / 720.0f, 1.0f / 5040.0f,
                            1.0f,
                            1.0f, 0.5f, 1.0f / 6.0f, 1.0f / 24.0f,
                            1.0f / 120.0f, 1.0f / 720.0f, 1.0f / 5040.0f};
    ps[t] = (red[t][0] + red[t][1] + red[t][2] + red[t][3]) * invf[t];
  }
  __syncthreads();
  float q1 = ps[0], q2 = ps[1], q3 = ps[2], q4 = ps[3];
  float q5 = ps[4], q6 = ps[5], q7 = ps[6];
  float T = ps[7];
  float p1 = ps[8], p2 = ps[9], p3 = ps[10], p4 = ps[11];
  float p5 = ps[12], p6 = ps[13], p7 = ps[14];

  float* ob = out + (size_t)bc * N_;
  #pragma unroll
  for (int it = 0; it < 4; ++it) {
    float o4[4];
    #pragma unroll
    for (int e = 0; e < 4; ++e) {
      float alpha = gm * v[it * 4 + e];
      float hn = p7;
      hn = fmaf(alpha, hn, p6);
      hn = fmaf(alpha, hn, p5);
      hn = fmaf(alpha, hn, p4);
      hn = fmaf(alpha, hn, p3);
      hn = fmaf(alpha, hn, p2);
      hn = fmaf(alpha, hn, p1);
      float numer = fmaf(alpha, hn, T);
      float hd = q7;
      hd = fmaf(alpha, hd, q6);
      hd = fmaf(alpha, hd, q5);
      hd = fmaf(alpha, hd, q4);
      hd = fmaf(alpha, hd, q3);
      hd = fmaf(alpha, hd, q2);
      hd = fmaf(alpha, hd, q1);
      float denom = fmaf(alpha, hd, (float)N_);
      o4[e] = numer / denom;
    }
    *(float4*)&ob[it * 1024 + t * 4] = make_float4(o4[0], o4[1], o4[2], o4[3]);
  }
}

extern "C" void kernel_launch(void* const* d_in, const int* in_sizes, int n_in,
                              void* d_out, int out_size, void* d_ws, size_t ws_size,
                              hipStream_t stream) {
  (void)in_sizes; (void)n_in; (void)out_size; (void)ws_size;
  const float* x   = (const float*)d_in[0];
  const float* w1  = (const float*)d_in[1];
  const float* b1  = (const float*)d_in[2];
  const float* gam = (const float*)d_in[3];
  const float* bet = (const float*)d_in[4];
  const float* mea = (const float*)d_in[5];
  const float* var = (const float*)d_in[6];
  const float* wh  = (const float*)d_in[7];
  const float* bh  = (const float*)d_in[8];
  const float* ww  = (const float*)d_in[9];
  const float* bw  = (const float*)d_in[10];
  const float* wd1 = (const float*)d_in[11];
  const float* bd1 = (const float*)d_in[12];
  const float* wd2 = (const float*)d_in[13];
  const float* bd2 = (const float*)d_in[14];
  const float* msk = (const float*)d_in[15];
  float* out = (float*)d_out;

  float* ws = (float*)d_ws;
  float*    xhT      = ws;                            // 65536 floats
  unsigned* flags    = (unsigned*)(ws + 65536);       // 512
  unsigned* rowflags = flags + 512;                   // 256
  float*    ahb      = ws + 65536 + 768;              // 128
  float*    swb      = ahb + 128;                     // 128
  float*    sdb      = swb + 128;                     // 128

  hipLaunchKernelGGL(k_one, dim3(B_ * C_), dim3(256), 0, stream,
                     x, w1, b1, gam, bet, mea, var,
                     wh, bh, ww, bw, wd1, bd1, wd2, bd2, msk,
                     xhT, flags, rowflags, ahb, swb, sdb, out);
}

// Round 11
// 38.755 us; speedup vs baseline: 4.9872x; 1.3403x over previous
//
#include <hip/hip_runtime.h>

#define B_ 2
#define C_ 256
#define HW_ 64
#define N_ 4096
#define K_SEL 1228   // int(4096*0.3)
#define MIP_ 16

__device__ __forceinline__ float sigm(float z) { return 1.0f / (1.0f + expf(-z)); }

// ---------------------------------------------------------------- k_pre
// One block per (b,c): row means and col means, stored TRANSPOSED:
// xhT[((b*2+seg)*64 + pos)*256 + c],  seg 0 = row-mean (x_h), 1 = col-mean (x_w)
__global__ __launch_bounds__(256) void k_pre(const float* __restrict__ x,
                                             float* __restrict__ xhT) {
  __shared__ float rp[64][17];
  __shared__ float cp[16][65];
  int bc = blockIdx.x, t = threadIdx.x;
  int b = bc >> 8, c = bc & 255;
  const float* src = x + (size_t)bc * N_;
  int g = t >> 4, b16 = t & 15;
  float c0 = 0, c1 = 0, c2 = 0, c3 = 0;
  #pragma unroll
  for (int it = 0; it < 4; ++it) {
    int row = it * 16 + g;
    float4 v = *(const float4*)&src[row * 64 + b16 * 4];
    rp[row][b16] = v.x + v.y + v.z + v.w;
    c0 += v.x; c1 += v.y; c2 += v.z; c3 += v.w;
  }
  cp[g][b16 * 4 + 0] = c0;
  cp[g][b16 * 4 + 1] = c1;
  cp[g][b16 * 4 + 2] = c2;
  cp[g][b16 * 4 + 3] = c3;
  __syncthreads();
  if (t < 64) {
    float rs = 0;
    #pragma unroll
    for (int i = 0; i < 16; ++i) rs += rp[t][i];
    xhT[(((b * 2 + 0) * 64 + t) << 8) + c] = rs * (1.0f / 64.0f);
    float cs = 0;
    #pragma unroll
    for (int gg = 0; gg < 16; ++gg) cs += cp[gg][t];
    xhT[(((b * 2 + 1) * 64 + t) << 8) + c] = cs * (1.0f / 64.0f);
  }
}

// ---------------------------------------------------------------- k_fin2
// One block per (b,c). Redundantly computes conv+BN+ReLU+dots+sigmoids from
// xhT (every block, deterministic, no sync), then the validated selection +
// moments + output.
__global__ __launch_bounds__(256) void k_fin2(
    const float* __restrict__ x, const float* __restrict__ xhT,
    const float* __restrict__ w1, const float* __restrict__ b1,
    const float* __restrict__ gam, const float* __restrict__ bet,
    const float* __restrict__ mea, const float* __restrict__ var,
    const float* __restrict__ wh, const float* __restrict__ bh,
    const float* __restrict__ ww, const float* __restrict__ bw,
    const float* __restrict__ wd1, const float* __restrict__ bd1,
    const float* __restrict__ wd2, const float* __restrict__ bd2,
    const float* __restrict__ msk,
    float* __restrict__ out) {
  __shared__ float dpart[2][128][4];
  __shared__ float ahs[HW_], sds[HW_], sws[HW_], sps[HW_];
  __shared__ int icomb[4];
  __shared__ float fmn[4], fmx[4];
  __shared__ float red[15][4];
  __shared__ float ps[15];

  int bc = blockIdx.x, t = threadIdx.x;
  int b = bc >> 8;

  // prefetch this block's image (16 floats/thread) — hides under conv
  const float* xr = x + (size_t)bc * N_;
  float4 xv[4];
  #pragma unroll
  for (int it = 0; it < 4; ++it)
    xv[it] = *(const float4*)&xr[it * 1024 + t * 4];

  // ===== redundant conv+BN+ReLU+dots (validated round-8 Stage B)
  {
    int p = t & 127;
    int oh = __builtin_amdgcn_readfirstlane(t >> 7);   // wave-uniform
    int seg = p >> 6, pos = p & 63;
    const float* yrow = xhT + (((b * 2 + seg) * 64 + pos) << 8);
    const float* wb = w1 + oh * 8 * C_;                // uniform -> s_loads
    float r8[8] = {0, 0, 0, 0, 0, 0, 0, 0};
    #pragma unroll 4
    for (int c4 = 0; c4 < 64; ++c4) {
      float4 y4 = *(const float4*)&yrow[c4 * 4];
      const float ye[4] = {y4.x, y4.y, y4.z, y4.w};
      #pragma unroll
      for (int e = 0; e < 4; ++e) {
        int cc = c4 * 4 + e;
        #pragma unroll
        for (int oo = 0; oo < 8; ++oo)
          r8[oo] = fmaf(wb[oo * C_ + cc], ye[e], r8[oo]);
      }
    }
    float dH = 0, dW = 0, dD1 = 0, dD2 = 0;
    #pragma unroll
    for (int oo = 0; oo < 8; ++oo) {
      int o = oh * 8 + oo;
      float sc = gam[o] * rsqrtf(var[o] + 1e-5f);
      float y = r8[oo] + b1[o] - mea[o];
      float rr = fmaxf(fmaf(y, sc, bet[o]), 0.0f);
      dH = fmaf(wh[o], rr, dH);
      dW = fmaf(ww[o], rr, dW);
      dD1 = fmaf(wd1[o], rr, dD1);
      dD2 = fmaf(wd2[o], rr, dD2);
    }
    dpart[oh][p][0] = dH; dpart[oh][p][1] = dW;
    dpart[oh][p][2] = dD1; dpart[oh][p][3] = dD2;
  }
  __syncthreads();
  if (t < 128) {
    int seg = t >> 6, pos = t & 63;
    float aH = bh[0] + dpart[0][t][0] + dpart[1][t][0];
    float aW = bw[0] + dpart[0][t][1] + dpart[1][t][1];
    float aD1 = bd1[0] + dpart[0][t][2] + dpart[1][t][2];
    float aD2 = bd2[0] + dpart[0][t][3] + dpart[1][t][3];
    if (seg == 0) {
      ahs[pos] = sigm(aH);
      sds[pos] = sigm(aD1) * sigm(aD2);
    } else {
      sws[pos] = sigm(aW);
    }
  }
  __syncthreads();
  if (t < 64) sps[t] = sws[t] * sds[t];
  __syncthreads();

  // ===== Stage C: selection + moments + output (validated)
  float4 sp4 = *(const float4*)&sps[(t * 4) & 63];
  const float spe[4] = {sp4.x, sp4.y, sp4.z, sp4.w};
  float ahv[4];
  #pragma unroll
  for (int it = 0; it < 4; ++it) ahv[it] = ahs[it * 16 + (t >> 4)];

  float v[16];
  #pragma unroll
  for (int it = 0; it < 4; ++it)
    #pragma unroll
    for (int e = 0; e < 4; ++e) v[it * 4 + e] = ahv[it] * spe[e];

  float mn = v[0], mx = v[0];
  #pragma unroll
  for (int k = 1; k < 16; ++k) { mn = fminf(mn, v[k]); mx = fmaxf(mx, v[k]); }
  #pragma unroll
  for (int o = 32; o; o >>= 1) {
    mn = fminf(mn, __shfl_xor(mn, o, 64));
    mx = fmaxf(mx, __shfl_xor(mx, o, 64));
  }
  if ((t & 63) == 0) { fmn[t >> 6] = mn; fmx[t >> 6] = mx; }
  __syncthreads();
  mn = fminf(fminf(fmn[0], fmn[1]), fminf(fmn[2], fmn[3]));
  mx = fmaxf(fmaxf(fmx[0], fmx[1]), fmaxf(fmx[2], fmx[3]));

  unsigned lo = __float_as_uint(mn);        // cnt_ge(lo) = 4096 >= K
  unsigned hi = __float_as_uint(mx) + 1u;   // cnt_ge(hi) = 0 < K
  while (hi - lo > 8192u) {
    unsigned mid = lo + ((hi - lo) >> 1);
    float midf = __uint_as_float(mid);
    int cnt = 0;
    #pragma unroll
    for (int k = 0; k < 16; ++k) cnt += (v[k] >= midf) ? 1 : 0;
    #pragma unroll
    for (int o = 32; o; o >>= 1) cnt += __shfl_xor(cnt, o, 64);
    if ((t & 63) == 0) icomb[t >> 6] = cnt;
    __syncthreads();
    int total = icomb[0] + icomb[1] + icomb[2] + icomb[3];
    __syncthreads();
    if (total >= K_SEL) lo = mid; else hi = mid;
  }
  float thr = __uint_as_float(lo);
  float gm = sigm(msk[0]);

  // acc[0..6] = q1..q7, acc[7] = T, acc[8..14] = P1..P7
  float acc[15];
  #pragma unroll
  for (int m = 0; m < 15; ++m) acc[m] = 0.0f;
  #pragma unroll
  for (int it = 0; it < 4; ++it) {
    const float xe[4] = {xv[it].x, xv[it].y, xv[it].z, xv[it].w};
    #pragma unroll
    for (int e = 0; e < 4; ++e) {
      float vv = v[it * 4 + e];
      float xx = xe[e];
      acc[7] += xx;
      if (vv >= thr) {
        float p = vv;
        acc[0] += p;
        acc[8] = fmaf(p, xx, acc[8]); p *= vv;
        acc[1] += p;
        acc[9] = fmaf(p, xx, acc[9]); p *= vv;
        acc[2] += p;
        acc[10] = fmaf(p, xx, acc[10]); p *= vv;
        acc[3] += p;
        acc[11] = fmaf(p, xx, acc[11]); p *= vv;
        acc[4] += p;
        acc[12] = fmaf(p, xx, acc[12]); p *= vv;
        acc[5] += p;
        acc[13] = fmaf(p, xx, acc[13]); p *= vv;
        acc[6] += p;
        acc[14] = fmaf(p, xx, acc[14]);
      }
    }
  }
  #pragma unroll
  for (int m = 0; m < 15; ++m) {
    float s = acc[m];
    #pragma unroll
    for (int o = 32; o; o >>= 1) s += __shfl_xor(s, o, 64);
    if ((t & 63) == 0) red[m][t >> 6] = s;
  }
  __syncthreads();
  if (t < 15) {
    const float invf[15] = {1.0f, 0.5f, 1.0f / 6.0f, 1.0f / 24.0f,
                            1.0f / 120.0f, 1.0f / 720.0f, 1.0f / 5040.0f,
                            1.0f,
                            1.0f, 0.5f, 1.0f / 6.0f, 1.0f / 24.0f,
                            1.0f / 120.0f, 1.0f / 720.0f, 1.0f / 5040.0f};
    ps[t] = (red[t][0] + red[t][1] + red[t][2] + red[t][3]) * invf[t];
  }
  __syncthreads();
  float q1 = ps[0], q2 = ps[1], q3 = ps[2], q4 = ps[3];
  float q5 = ps[4], q6 = ps[5], q7 = ps[6];
  float T = ps[7];
  float p1 = ps[8], p2 = ps[9], p3 = ps[10], p4 = ps[11];
  float p5 = ps[12], p6 = ps[13], p7 = ps[14];

  float* ob = out + (size_t)bc * N_;
  #pragma unroll
  for (int it = 0; it < 4; ++it) {
    float o4[4];
    #pragma unroll
    for (int e = 0; e < 4; ++e) {
      float alpha = gm * v[it * 4 + e];
      float hn = p7;
      hn = fmaf(alpha, hn, p6);
      hn = fmaf(alpha, hn, p5);
      hn = fmaf(alpha, hn, p4);
      hn = fmaf(alpha, hn, p3);
      hn = fmaf(alpha, hn, p2);
      hn = fmaf(alpha, hn, p1);
      float numer = fmaf(alpha, hn, T);
      float hd = q7;
      hd = fmaf(alpha, hd, q6);
      hd = fmaf(alpha, hd, q5);
      hd = fmaf(alpha, hd, q4);
      hd = fmaf(alpha, hd, q3);
      hd = fmaf(alpha, hd, q2);
      hd = fmaf(alpha, hd, q1);
      float denom = fmaf(alpha, hd, (float)N_);
      o4[e] = numer / denom;
    }
    *(float4*)&ob[it * 1024 + t * 4] = make_float4(o4[0], o4[1], o4[2], o4[3]);
  }
}

extern "C" void kernel_launch(void* const* d_in, const int* in_sizes, int n_in,
                              void* d_out, int out_size, void* d_ws, size_t ws_size,
                              hipStream_t stream) {
  (void)in_sizes; (void)n_in; (void)out_size; (void)ws_size;
  const float* x   = (const float*)d_in[0];
  const float* w1  = (const float*)d_in[1];
  const float* b1  = (const float*)d_in[2];
  const float* gam = (const float*)d_in[3];
  const float* bet = (const float*)d_in[4];
  const float* mea = (const float*)d_in[5];
  const float* var = (const float*)d_in[6];
  const float* wh  = (const float*)d_in[7];
  const float* bh  = (const float*)d_in[8];
  const float* ww  = (const float*)d_in[9];
  const float* bw  = (const float*)d_in[10];
  const float* wd1 = (const float*)d_in[11];
  const float* bd1 = (const float*)d_in[12];
  const float* wd2 = (const float*)d_in[13];
  const float* bd2 = (const float*)d_in[14];
  const float* msk = (const float*)d_in[15];
  float* out = (float*)d_out;

  float* xhT = (float*)d_ws;   // 65536 floats

  hipLaunchKernelGGL(k_pre, dim3(B_ * C_), dim3(256), 0, stream, x, xhT);
  hipLaunchKernelGGL(k_fin2, dim3(B_ * C_), dim3(256), 0, stream,
                     x, xhT, w1, b1, gam, bet, mea, var,
                     wh, bh, ww, bw, wd1, bd1, wd2, bd2, msk, out);
}

// Round 12
// 33.503 us; speedup vs baseline: 5.7692x; 1.1568x over previous
//
#include <hip/hip_runtime.h>

#define B_ 2
#define C_ 256
#define HW_ 64
#define N_ 4096
#define K_SEL 1228   // int(4096*0.3)
#define MIP_ 16

__device__ __forceinline__ float sigm(float z) { return 1.0f / (1.0f + expf(-z)); }

// ---------------------------------------------------------------- k_pre
// One block per (b,c): row means and col means, natural layout:
// Y[((b*2+seg)*256 + c)*64 + pos],  seg 0 = row-mean (x_h), 1 = col-mean (x_w)
__global__ __launch_bounds__(256) void k_pre(const float* __restrict__ x,
                                             float* __restrict__ Y) {
  __shared__ float rp[64][17];
  __shared__ float cp[16][65];
  int bc = blockIdx.x, t = threadIdx.x;
  int b = bc >> 8, c = bc & 255;
  const float* src = x + (size_t)bc * N_;
  int g = t >> 4, b16 = t & 15;
  float c0 = 0, c1 = 0, c2 = 0, c3 = 0;
  #pragma unroll
  for (int it = 0; it < 4; ++it) {
    int row = it * 16 + g;
    float4 v = *(const float4*)&src[row * 64 + b16 * 4];
    rp[row][b16] = v.x + v.y + v.z + v.w;
    c0 += v.x; c1 += v.y; c2 += v.z; c3 += v.w;
  }
  cp[g][b16 * 4 + 0] = c0;
  cp[g][b16 * 4 + 1] = c1;
  cp[g][b16 * 4 + 2] = c2;
  cp[g][b16 * 4 + 3] = c3;
  __syncthreads();
  if (t < 64) {
    float rs = 0;
    #pragma unroll
    for (int i = 0; i < 16; ++i) rs += rp[t][i];
    Y[(((b * 2 + 0) << 8) + c) * 64 + t] = rs * (1.0f / 64.0f);
    float cs = 0;
    #pragma unroll
    for (int gg = 0; gg < 16; ++gg) cs += cp[gg][t];
    Y[(((b * 2 + 1) << 8) + c) * 64 + t] = cs * (1.0f / 64.0f);
  }
}

// ---------------------------------------------------------------- k_fin2
// One block per (b,c). Redundant conv (wave-coalesced reads: wave = (seg,oh),
// lane = pos; per-c 256B contiguous load + 8 FMA vs s_load weights), then
// the validated selection + moments + output.
__global__ __launch_bounds__(256) void k_fin2(
    const float* __restrict__ x, const float* __restrict__ Y,
    const float* __restrict__ w1, const float* __restrict__ b1,
    const float* __restrict__ gam, const float* __restrict__ bet,
    const float* __restrict__ mea, const float* __restrict__ var,
    const float* __restrict__ wh, const float* __restrict__ bh,
    const float* __restrict__ ww, const float* __restrict__ bw,
    const float* __restrict__ wd1, const float* __restrict__ bd1,
    const float* __restrict__ wd2, const float* __restrict__ bd2,
    const float* __restrict__ msk,
    float* __restrict__ out) {
  __shared__ float dpart[2][128][4];
  __shared__ float ahs[HW_], sds[HW_], sws[HW_], sps[HW_];
  __shared__ int icomb[4];
  __shared__ float fmn[4], fmx[4];
  __shared__ float red[15][4];
  __shared__ float ps[15];

  int bc = blockIdx.x, t = threadIdx.x;
  int b = bc >> 8;

  // prefetch this block's image (16 floats/thread) — hides under conv
  const float* xr = x + (size_t)bc * N_;
  float4 xv[4];
  #pragma unroll
  for (int it = 0; it < 4; ++it)
    xv[it] = *(const float4*)&xr[it * 1024 + t * 4];

  // ===== redundant conv, wave-coalesced
  {
    int pos = t & 63;
    int w = t >> 6;                                     // 0..3
    int seg = w & 1;
    int oh = __builtin_amdgcn_readfirstlane(w >> 1);    // wave-uniform 0/1
    const float* ybase = Y + (((size_t)(b * 2 + seg)) << 14) + pos; // + c*64
    const float* wb = w1 + oh * 8 * C_;                 // uniform -> s_loads
    float r8[8] = {0, 0, 0, 0, 0, 0, 0, 0};
    #pragma unroll 8
    for (int c = 0; c < C_; ++c) {
      float yv = ybase[c * 64];
      #pragma unroll
      for (int oo = 0; oo < 8; ++oo)
        r8[oo] = fmaf(wb[oo * C_ + c], yv, r8[oo]);
    }
    float dH = 0, dW = 0, dD1 = 0, dD2 = 0;
    #pragma unroll
    for (int oo = 0; oo < 8; ++oo) {
      int o = oh * 8 + oo;
      float sc = gam[o] * rsqrtf(var[o] + 1e-5f);
      float y = r8[oo] + b1[o] - mea[o];
      float rr = fmaxf(fmaf(y, sc, bet[o]), 0.0f);
      dH = fmaf(wh[o], rr, dH);
      dW = fmaf(ww[o], rr, dW);
      dD1 = fmaf(wd1[o], rr, dD1);
      dD2 = fmaf(wd2[o], rr, dD2);
    }
    int p = seg * 64 + pos;   // == t & 127
    dpart[oh][p][0] = dH; dpart[oh][p][1] = dW;
    dpart[oh][p][2] = dD1; dpart[oh][p][3] = dD2;
  }
  __syncthreads();
  if (t < 128) {
    int seg = t >> 6, pos = t & 63;
    float aH = bh[0] + dpart[0][t][0] + dpart[1][t][0];
    float aW = bw[0] + dpart[0][t][1] + dpart[1][t][1];
    float aD1 = bd1[0] + dpart[0][t][2] + dpart[1][t][2];
    float aD2 = bd2[0] + dpart[0][t][3] + dpart[1][t][3];
    if (seg == 0) {
      ahs[pos] = sigm(aH);
      sds[pos] = sigm(aD1) * sigm(aD2);
    } else {
      sws[pos] = sigm(aW);
    }
  }
  __syncthreads();
  if (t < 64) sps[t] = sws[t] * sds[t];
  __syncthreads();

  // ===== Stage C: selection + moments + output (validated)
  float4 sp4 = *(const float4*)&sps[(t * 4) & 63];
  const float spe[4] = {sp4.x, sp4.y, sp4.z, sp4.w};
  float ahv[4];
  #pragma unroll
  for (int it = 0; it < 4; ++it) ahv[it] = ahs[it * 16 + (t >> 4)];

  float v[16];
  #pragma unroll
  for (int it = 0; it < 4; ++it)
    #pragma unroll
    for (int e = 0; e < 4; ++e) v[it * 4 + e] = ahv[it] * spe[e];

  float mn = v[0], mx = v[0];
  #pragma unroll
  for (int k = 1; k < 16; ++k) { mn = fminf(mn, v[k]); mx = fmaxf(mx, v[k]); }
  #pragma unroll
  for (int o = 32; o; o >>= 1) {
    mn = fminf(mn, __shfl_xor(mn, o, 64));
    mx = fmaxf(mx, __shfl_xor(mx, o, 64));
  }
  if ((t & 63) == 0) { fmn[t >> 6] = mn; fmx[t >> 6] = mx; }
  __syncthreads();
  mn = fminf(fminf(fmn[0], fmn[1]), fminf(fmn[2], fmn[3]));
  mx = fmaxf(fmaxf(fmx[0], fmx[1]), fmaxf(fmx[2], fmx[3]));

  unsigned lo = __float_as_uint(mn);        // cnt_ge(lo) = 4096 >= K
  unsigned hi = __float_as_uint(mx) + 1u;   // cnt_ge(hi) = 0 < K
  while (hi - lo > 8192u) {
    unsigned mid = lo + ((hi - lo) >> 1);
    float midf = __uint_as_float(mid);
    int cnt = 0;
    #pragma unroll
    for (int k = 0; k < 16; ++k) cnt += (v[k] >= midf) ? 1 : 0;
    #pragma unroll
    for (int o = 32; o; o >>= 1) cnt += __shfl_xor(cnt, o, 64);
    if ((t & 63) == 0) icomb[t >> 6] = cnt;
    __syncthreads();
    int total = icomb[0] + icomb[1] + icomb[2] + icomb[3];
    __syncthreads();
    if (total >= K_SEL) lo = mid; else hi = mid;
  }
  float thr = __uint_as_float(lo);
  float gm = sigm(msk[0]);

  // acc[0..6] = q1..q7, acc[7] = T, acc[8..14] = P1..P7
  float acc[15];
  #pragma unroll
  for (int m = 0; m < 15; ++m) acc[m] = 0.0f;
  #pragma unroll
  for (int it = 0; it < 4; ++it) {
    const float xe[4] = {xv[it].x, xv[it].y, xv[it].z, xv[it].w};
    #pragma unroll
    for (int e = 0; e < 4; ++e) {
      float vv = v[it * 4 + e];
      float xx = xe[e];
      acc[7] += xx;
      if (vv >= thr) {
        float p = vv;
        acc[0] += p;
        acc[8] = fmaf(p, xx, acc[8]); p *= vv;
        acc[1] += p;
        acc[9] = fmaf(p, xx, acc[9]); p *= vv;
        acc[2] += p;
        acc[10] = fmaf(p, xx, acc[10]); p *= vv;
        acc[3] += p;
        acc[11] = fmaf(p, xx, acc[11]); p *= vv;
        acc[4] += p;
        acc[12] = fmaf(p, xx, acc[12]); p *= vv;
        acc[5] += p;
        acc[13] = fmaf(p, xx, acc[13]); p *= vv;
        acc[6] += p;
        acc[14] = fmaf(p, xx, acc[14]);
      }
    }
  }
  #pragma unroll
  for (int m = 0; m < 15; ++m) {
    float s = acc[m];
    #pragma unroll
    for (int o = 32; o; o >>= 1) s += __shfl_xor(s, o, 64);
    if ((t & 63) == 0) red[m][t >> 6] = s;
  }
  __syncthreads();
  if (t < 15) {
    const float invf[15] = {1.0f, 0.5f, 1.0f / 6.0f, 1.0f / 24.0f,
                            1.0f / 120.0f, 1.0f / 720.0f, 1.0f / 5040.0f,
                            1.0f,
                            1.0f, 0.5f, 1.0f / 6.0f, 1.0f / 24.0f,
                            1.0f / 120.0f, 1.0f / 720.0f, 1.0f / 5040.0f};
    ps[t] = (red[t][0] + red[t][1] + red[t][2] + red[t][3]) * invf[t];
  }
  __syncthreads();
  float q1 = ps[0], q2 = ps[1], q3 = ps[2], q4 = ps[3];
  float q5 = ps[4], q6 = ps[5], q7 = ps[6];
  float T = ps[7];
  float p1 = ps[8], p2 = ps[9], p3 = ps[10], p4 = ps[11];
  float p5 = ps[12], p6 = ps[13], p7 = ps[14];

  float* ob = out + (size_t)bc * N_;
  #pragma unroll
  for (int it = 0; it < 4; ++it) {
    float o4[4];
    #pragma unroll
    for (int e = 0; e < 4; ++e) {
      float alpha = gm * v[it * 4 + e];
      float hn = p7;
      hn = fmaf(alpha, hn, p6);
      hn = fmaf(alpha, hn, p5);
      hn = fmaf(alpha, hn, p4);
      hn = fmaf(alpha, hn, p3);
      hn = fmaf(alpha, hn, p2);
      hn = fmaf(alpha, hn, p1);
      float numer = fmaf(alpha, hn, T);
      float hd = q7;
      hd = fmaf(alpha, hd, q6);
      hd = fmaf(alpha, hd, q5);
      hd = fmaf(alpha, hd, q4);
      hd = fmaf(alpha, hd, q3);
      hd = fmaf(alpha, hd, q2);
      hd = fmaf(alpha, hd, q1);
      float denom = fmaf(alpha, hd, (float)N_);
      o4[e] = numer / denom;
    }
    *(float4*)&ob[it * 1024 + t * 4] = make_float4(o4[0], o4[1], o4[2], o4[3]);
  }
}

extern "C" void kernel_launch(void* const* d_in, const int* in_sizes, int n_in,
                              void* d_out, int out_size, void* d_ws, size_t ws_size,
                              hipStream_t stream) {
  (void)in_sizes; (void)n_in; (void)out_size; (void)ws_size;
  const float* x   = (const float*)d_in[0];
  const float* w1  = (const float*)d_in[1];
  const float* b1  = (const float*)d_in[2];
  const float* gam = (const float*)d_in[3];
  const float* bet = (const float*)d_in[4];
  const float* mea = (const float*)d_in[5];
  const float* var = (const float*)d_in[6];
  const float* wh  = (const float*)d_in[7];
  const float* bh  = (const float*)d_in[8];
  const float* ww  = (const float*)d_in[9];
  const float* bw  = (const float*)d_in[10];
  const float* wd1 = (const float*)d_in[11];
  const float* bd1 = (const float*)d_in[12];
  const float* wd2 = (const float*)d_in[13];
  const float* bd2 = (const float*)d_in[14];
  const float* msk = (const float*)d_in[15];
  float* out = (float*)d_out;

  float* Y = (float*)d_ws;   // 65536 floats

  hipLaunchKernelGGL(k_pre, dim3(B_ * C_), dim3(256), 0, stream, x, Y);
  hipLaunchKernelGGL(k_fin2, dim3(B_ * C_), dim3(256), 0, stream,
                     x, Y, w1, b1, gam, bet, mea, var,
                     wh, bh, ww, bw, wd1, bd1, wd2, bd2, msk, out);
}